// Round 1
// baseline (58.495 us; speedup 1.0000x reference)
//
#include <hip/hip_runtime.h>
#include <math.h>

#define HW 256
#define TILE_W 64
#define TILE_H 16
#define HALO 2
#define LW (TILE_W + 2 * HALO)   // 68
#define LH (TILE_H + 2 * HALO)   // 20

__device__ __forceinline__ int reflect_idx(int i) {
    i = (i < 0) ? -i : i;
    i = (i >= HW) ? (2 * HW - 2 - i) : i;
    return i;
}

__global__ __launch_bounds__(256, 4)
void maxmedian_kernel(const float* __restrict__ x,
                      const float* __restrict__ mix,
                      const float* __restrict__ beta_raw,
                      float* __restrict__ out,
                      int C) {
    __shared__ float tile[LH * LW];

    const int tiles_x = HW / TILE_W;                 // 4
    const int tiles_y = HW / TILE_H;                 // 16
    const int tiles_per_plane = tiles_x * tiles_y;   // 64
    const int plane = blockIdx.x / tiles_per_plane;
    const int t     = blockIdx.x % tiles_per_plane;
    const int ty0 = (t / tiles_x) * TILE_H;
    const int tx0 = (t % tiles_x) * TILE_W;

    const float* __restrict__ xp = x + (size_t)plane * HW * HW;

    // Stage tile + halo into LDS with reflect padding applied.
    for (int i = threadIdx.x; i < LH * LW; i += 256) {
        const int r = i / LW;
        const int c = i - r * LW;
        const int gr = reflect_idx(ty0 + r - HALO);
        const int gc = reflect_idx(tx0 + c - HALO);
        tile[i] = xp[gr * HW + gc];
    }
    __syncthreads();

    const int ch = plane % C;
    const float lam  = 1.0f / (1.0f + __expf(-mix[ch]));
    const float beta = 5.0f + 45.0f / (1.0f + __expf(-beta_raw[0]));
    const float nbl2e = -beta * 1.44269504088896f;   // -beta * log2(e)

    const int tx   = threadIdx.x & 63;   // 0..63 (column within tile)
    const int tyq  = threadIdx.x >> 6;   // 0..3
    const int row0 = tyq * 4;            // first of 4 output rows (tile-local)

    // 5x5 register window for output row row0+s; LDS rows row0+s .. row0+s+4.
    float w[5][5];
    #pragma unroll
    for (int dy = 0; dy < 5; ++dy) {
        #pragma unroll
        for (int dx = 0; dx < 5; ++dx) {
            w[dy][dx] = tile[(row0 + dy) * LW + tx + dx];
        }
    }

    float* __restrict__ orow =
        out + (size_t)plane * HW * HW + (size_t)(ty0 + row0) * HW + (tx0 + tx);

    #pragma unroll
    for (int s = 0; s < 4; ++s) {
        // Pass A: sum + max over the 25-element window.
        float sum = 0.0f;
        float mx  = -INFINITY;
        #pragma unroll
        for (int dy = 0; dy < 5; ++dy) {
            #pragma unroll
            for (int dx = 0; dx < 5; ++dx) {
                const float v = w[(s + dy) % 5][dx];   // compile-time index
                sum += v;
                mx = fmaxf(mx, v);
            }
        }
        const float mean = sum * (1.0f / 25.0f);

        // Pass B: softmax(-beta*|v-mean|)-weighted sum (normalization makes
        // the max-subtraction cancel; args bounded, no underflow for this data).
        float wsum = 0.0f, wacc = 0.0f;
        #pragma unroll
        for (int dy = 0; dy < 5; ++dy) {
            #pragma unroll
            for (int dx = 0; dx < 5; ++dx) {
                const float v = w[(s + dy) % 5][dx];
                const float a = fabsf(v - mean);
                const float e = __builtin_amdgcn_exp2f(a * nbl2e);
                wsum += e;
                wacc = fmaf(e, v, wacc);
            }
        }
        const float med = wacc / wsum;

        orow[(size_t)s * HW] = fmaf(lam, med - mx, mx);  // lam*med + (1-lam)*mx

        // Slide window down one row: refill the vacated register row.
        if (s < 3) {
            #pragma unroll
            for (int dx = 0; dx < 5; ++dx) {
                w[s % 5][dx] = tile[(row0 + 5 + s) * LW + tx + dx];
            }
        }
    }
}

extern "C" void kernel_launch(void* const* d_in, const int* in_sizes, int n_in,
                              void* d_out, int out_size, void* d_ws, size_t ws_size,
                              hipStream_t stream) {
    const float* x        = (const float*)d_in[0];
    const float* mix      = (const float*)d_in[1];
    const float* beta_raw = (const float*)d_in[2];
    float* out            = (float*)d_out;

    const int planes = in_sizes[0] / (HW * HW);      // B*C = 128
    const int C      = in_sizes[1];                  // 32
    const int tiles_per_plane = (HW / TILE_W) * (HW / TILE_H);  // 64
    const int grid = planes * tiles_per_plane;       // 8192

    maxmedian_kernel<<<grid, 256, 0, stream>>>(x, mix, beta_raw, out, C);
}

// Round 2
// 45.776 us; speedup vs baseline: 1.2779x; 1.2779x over previous
//
#include <hip/hip_runtime.h>
#include <math.h>

#define HW 256
#define TW 128
#define TH 32
#define LW 132          // 2 halo + 128 + 2 halo (stride 528B = 33*16, keeps 16B alignment)
#define LH 36           // 2 halo + 32 + 2 halo

__device__ __forceinline__ int reflect_idx(int i) {
    i = (i < 0) ? -i : i;
    i = (i >= HW) ? (2 * HW - 2 - i) : i;
    return i;
}

__device__ __forceinline__ float4 max4(float4 a, float4 b) {
    float4 r; r.x = fmaxf(a.x, b.x); r.y = fmaxf(a.y, b.y);
    r.z = fmaxf(a.z, b.z); r.w = fmaxf(a.w, b.w); return r;
}
__device__ __forceinline__ float4 add4(float4 a, float4 b) {
    float4 r; r.x = a.x + b.x; r.y = a.y + b.y;
    r.z = a.z + b.z; r.w = a.w + b.w; return r;
}
__device__ __forceinline__ float4 sub4(float4 a, float4 b) {
    float4 r; r.x = a.x - b.x; r.y = a.y - b.y;
    r.z = a.z - b.z; r.w = a.w - b.w; return r;
}

// Process one output row for a 4-pixel group. A0..B4 are the 5 window rows
// (8 floats each as two float4s). csA/csB are running column sums (captured).
#define PROC_ROW(A0,B0,A1,B1,A2,B2,A3,B3,A4,B4, OUTROW)                         \
  do {                                                                          \
    const float4 cmA = max4(max4(max4(A0,A1), max4(A2,A3)), A4);                \
    const float4 cmB = max4(max4(max4(B0,B1), max4(B2,B3)), B4);                \
    const float csv[8] = {csA.x,csA.y,csA.z,csA.w, csB.x,csB.y,csB.z,csB.w};    \
    const float cmv[8] = {cmA.x,cmA.y,cmA.z,cmA.w, cmB.x,cmB.y,cmB.z,cmB.w};    \
    const float vv[5][8] = {                                                    \
      {A0.x,A0.y,A0.z,A0.w, B0.x,B0.y,B0.z,B0.w},                               \
      {A1.x,A1.y,A1.z,A1.w, B1.x,B1.y,B1.z,B1.w},                               \
      {A2.x,A2.y,A2.z,A2.w, B2.x,B2.y,B2.z,B2.w},                               \
      {A3.x,A3.y,A3.z,A3.w, B3.x,B3.y,B3.z,B3.w},                               \
      {A4.x,A4.y,A4.z,A4.w, B4.x,B4.y,B4.z,B4.w}};                              \
    float o[4];                                                                 \
    _Pragma("unroll")                                                           \
    for (int p = 0; p < 4; ++p) {                                               \
      const float sum  = csv[p]+csv[p+1]+csv[p+2]+csv[p+3]+csv[p+4];            \
      const float mean = sum * 0.04f;                                           \
      const float m = fmaxf(fmaxf(fmaxf(cmv[p],cmv[p+1]),                       \
                                  fmaxf(cmv[p+2],cmv[p+3])), cmv[p+4]);         \
      float wsum = 0.0f, wacc = 0.0f;                                           \
      _Pragma("unroll")                                                         \
      for (int k = 0; k < 5; ++k) {                                             \
        _Pragma("unroll")                                                       \
        for (int j = 0; j < 5; ++j) {                                           \
          const float d = vv[k][p+j] - mean;                                    \
          const float e = __builtin_amdgcn_exp2f(fabsf(d) * nbl2e);             \
          wsum += e;                                                            \
          wacc = fmaf(e, d, wacc);                                              \
        }                                                                       \
      }                                                                         \
      const float med = fmaf(wacc, __builtin_amdgcn_rcpf(wsum), mean);          \
      o[p] = fmaf(lam, med - m, m);                                             \
    }                                                                           \
    float4 o4; o4.x = o[0]; o4.y = o[1]; o4.z = o[2]; o4.w = o[3];              \
    *(float4*)(orow + (size_t)(OUTROW) * HW) = o4;                              \
  } while (0)

__global__ __launch_bounds__(256, 4)
void maxmedian_kernel(const float* __restrict__ x,
                      const float* __restrict__ mix,
                      const float* __restrict__ beta_raw,
                      float* __restrict__ out,
                      int C) {
    __shared__ __align__(16) float tile[LH * LW];

    const int tiles_x = HW / TW;                       // 2
    const int tiles_per_plane = tiles_x * (HW / TH);   // 16
    const int plane = blockIdx.x / tiles_per_plane;
    const int t     = blockIdx.x % tiles_per_plane;
    const int ty0 = (t / tiles_x) * TH;
    const int tx0 = (t % tiles_x) * TW;

    const float* __restrict__ xp = x + (size_t)plane * (HW * HW);
    const int tid = threadIdx.x;

    // ---- Stage (TH+4) x (TW+4) tile with reflect padding ----
    {
        // Main region: LDS cols 2..129 <-> global cols tx0..tx0+127 (always in-bounds)
        const int c  = tid & 127;
        const int r0 = tid >> 7;          // 0..1
        const int gx = tx0 + c;
        #pragma unroll
        for (int k = 0; k < 18; ++k) {
            const int r  = r0 + 2 * k;    // 0..35
            const int gy = reflect_idx(ty0 + r - 2);
            tile[r * LW + (c + 2)] = xp[gy * HW + gx];
        }
        // Halo columns: j in {0,1,130,131} x 36 rows = 144 elements
        if (tid < 144) {
            const int jj = tid & 3;
            const int j  = (jj < 2) ? jj : (128 + jj);
            const int r  = tid >> 2;      // 0..35
            const int gx2 = reflect_idx(tx0 + j - 2);
            const int gy2 = reflect_idx(ty0 + r - 2);
            tile[r * LW + j] = xp[gy2 * HW + gx2];
        }
    }
    __syncthreads();

    // ---- Parameters ----
    const int ch = plane % C;
    const float lam  = 1.0f / (1.0f + __expf(-mix[ch]));
    const float beta = 5.0f + 45.0f / (1.0f + __expf(-beta_raw[0]));
    const float nbl2e = -beta * 1.44269504088896f;     // -beta * log2(e)

    // ---- Each thread: 4-wide x 4-tall pixel group ----
    const int tx  = tid & 31;     // column group: output cols tx0 + 4*tx .. +3
    const int tyq = tid >> 5;     // 0..7
    const int r0 = tyq * 4;       // first tile-local output row

    // Window for output row r covers LDS rows r..r+4, LDS cols 4*tx..4*tx+7
    // (left halo of 2 built into the layout => 16B-aligned float4 reads).
    const float* lbase = &tile[r0 * LW + 4 * tx];

    float4 w0a = *(const float4*)(lbase + 0 * LW);
    float4 w0b = *(const float4*)(lbase + 0 * LW + 4);
    float4 w1a = *(const float4*)(lbase + 1 * LW);
    float4 w1b = *(const float4*)(lbase + 1 * LW + 4);
    float4 w2a = *(const float4*)(lbase + 2 * LW);
    float4 w2b = *(const float4*)(lbase + 2 * LW + 4);
    float4 w3a = *(const float4*)(lbase + 3 * LW);
    float4 w3b = *(const float4*)(lbase + 3 * LW + 4);
    float4 w4a = *(const float4*)(lbase + 4 * LW);
    float4 w4b = *(const float4*)(lbase + 4 * LW + 4);

    // Running column sums over the current 5 window rows.
    float4 csA = add4(add4(add4(w0a, w1a), add4(w2a, w3a)), w4a);
    float4 csB = add4(add4(add4(w0b, w1b), add4(w2b, w3b)), w4b);

    float* __restrict__ orow =
        out + (size_t)plane * (HW * HW) + (size_t)(ty0 + r0) * HW + (tx0 + 4 * tx);

    PROC_ROW(w0a,w0b, w1a,w1b, w2a,w2b, w3a,w3b, w4a,w4b, 0);
    {   // slide: window row (r0+0) out, (r0+5) in -> rotate into w0
        const float4 na = *(const float4*)(lbase + 5 * LW);
        const float4 nb = *(const float4*)(lbase + 5 * LW + 4);
        csA = add4(csA, sub4(na, w0a));
        csB = add4(csB, sub4(nb, w0b));
        w0a = na; w0b = nb;
    }
    PROC_ROW(w1a,w1b, w2a,w2b, w3a,w3b, w4a,w4b, w0a,w0b, 1);
    {
        const float4 na = *(const float4*)(lbase + 6 * LW);
        const float4 nb = *(const float4*)(lbase + 6 * LW + 4);
        csA = add4(csA, sub4(na, w1a));
        csB = add4(csB, sub4(nb, w1b));
        w1a = na; w1b = nb;
    }
    PROC_ROW(w2a,w2b, w3a,w3b, w4a,w4b, w0a,w0b, w1a,w1b, 2);
    {
        const float4 na = *(const float4*)(lbase + 7 * LW);
        const float4 nb = *(const float4*)(lbase + 7 * LW + 4);
        csA = add4(csA, sub4(na, w2a));
        csB = add4(csB, sub4(nb, w2b));
        w2a = na; w2b = nb;
    }
    PROC_ROW(w3a,w3b, w4a,w4b, w0a,w0b, w1a,w1b, w2a,w2b, 3);
}

extern "C" void kernel_launch(void* const* d_in, const int* in_sizes, int n_in,
                              void* d_out, int out_size, void* d_ws, size_t ws_size,
                              hipStream_t stream) {
    const float* x        = (const float*)d_in[0];
    const float* mix      = (const float*)d_in[1];
    const float* beta_raw = (const float*)d_in[2];
    float* out            = (float*)d_out;

    const int planes = in_sizes[0] / (HW * HW);                 // B*C = 128
    const int C      = in_sizes[1];                             // 32
    const int tiles_per_plane = (HW / TW) * (HW / TH);          // 16
    const int grid = planes * tiles_per_plane;                  // 2048

    maxmedian_kernel<<<grid, 256, 0, stream>>>(x, mix, beta_raw, out, C);
}

// Round 3
// 39.572 us; speedup vs baseline: 1.4782x; 1.1568x over previous
//
#include <hip/hip_runtime.h>
#include <math.h>

#define HW 256
#define TW 64
#define TH 32
#define LW 68           // 2 halo + 64 + 2 halo
#define LH 36           // 2 halo + 32 + 2 halo

__device__ __forceinline__ int reflect_idx(int i) {
    i = (i < 0) ? -i : i;
    i = (i >= HW) ? (2 * HW - 2 - i) : i;
    return i;
}

__device__ __forceinline__ float4 max4(float4 a, float4 b) {
    float4 r; r.x = fmaxf(a.x, b.x); r.y = fmaxf(a.y, b.y);
    r.z = fmaxf(a.z, b.z); r.w = fmaxf(a.w, b.w); return r;
}
// 3-input elementwise max -> v_max3_f32 per component
__device__ __forceinline__ float4 max34(float4 a, float4 b, float4 c) {
    float4 r; r.x = fmaxf(fmaxf(a.x, b.x), c.x); r.y = fmaxf(fmaxf(a.y, b.y), c.y);
    r.z = fmaxf(fmaxf(a.z, b.z), c.z); r.w = fmaxf(fmaxf(a.w, b.w), c.w); return r;
}
__device__ __forceinline__ float4 add4(float4 a, float4 b) {
    float4 r; r.x = a.x + b.x; r.y = a.y + b.y;
    r.z = a.z + b.z; r.w = a.w + b.w; return r;
}
__device__ __forceinline__ float4 sub4(float4 a, float4 b) {
    float4 r; r.x = a.x - b.x; r.y = a.y - b.y;
    r.z = a.z - b.z; r.w = a.w - b.w; return r;
}

// One output row, 4 pixels. 5 window rows (A=cols0-3, B=cols4-7), column
// maxes cm, column sums cs. bp = beta*log2e; c04b = 0.04*bp.
__device__ __forceinline__ void proc_row(
    float4 A0, float4 B0, float4 A1, float4 B1, float4 A2, float4 B2,
    float4 A3, float4 B3, float4 A4, float4 B4,
    float4 cmA, float4 cmB, float4 csA, float4 csB,
    float bp, float c04b, float inv_bp, float lam,
    float* __restrict__ orow)
{
    const float cs[8] = {csA.x,csA.y,csA.z,csA.w, csB.x,csB.y,csB.z,csB.w};
    const float cm[8] = {cmA.x,cmA.y,cmA.z,cmA.w, cmB.x,cmB.y,cmB.z,cmB.w};
    const float vv[5][8] = {
        {A0.x,A0.y,A0.z,A0.w, B0.x,B0.y,B0.z,B0.w},
        {A1.x,A1.y,A1.z,A1.w, B1.x,B1.y,B1.z,B1.w},
        {A2.x,A2.y,A2.z,A2.w, B2.x,B2.y,B2.z,B2.w},
        {A3.x,A3.y,A3.z,A3.w, B3.x,B3.y,B3.z,B3.w},
        {A4.x,A4.y,A4.z,A4.w, B4.x,B4.y,B4.z,B4.w}};

    // Sliding horizontal sums of the 8 column sums (5-wide windows)
    const float t12 = cs[1] + cs[2];
    const float t34 = cs[3] + cs[4];
    const float t56 = cs[5] + cs[6];
    const float u   = t12 + t34;
    const float w_  = t34 + t56;
    const float S[4] = {cs[0] + u, u + cs[5], cs[2] + w_, w_ + cs[7]};

    // Horizontal max of 5 column-maxes with shared pairs (v_max3 fusion)
    const float h12 = fmaxf(cm[1], cm[2]);
    const float h34 = fmaxf(cm[3], cm[4]);
    const float h56 = fmaxf(cm[5], cm[6]);
    const float m[4] = {fmaxf(fmaxf(cm[0], h12), h34),
                        fmaxf(fmaxf(h12, h34), cm[5]),
                        fmaxf(fmaxf(cm[2], h34), h56),
                        fmaxf(fmaxf(h34, h56), cm[7])};

    float bm[4], ws[4], wa[4];
    #pragma unroll
    for (int p = 0; p < 4; ++p) { bm[p] = S[p] * c04b; ws[p] = 0.0f; wa[p] = 0.0f; }

    #pragma unroll
    for (int k = 0; k < 5; ++k) {
        #pragma unroll
        for (int j = 0; j < 5; ++j) {
            #pragma unroll
            for (int p = 0; p < 4; ++p) {
                const float tv = fmaf(bp, vv[k][p + j], -bm[p]);     // beta'*(v-mean)
                const float e  = __builtin_amdgcn_exp2f(-fabsf(tv)); // -|t| via src mod
                ws[p] += e;
                wa[p] = fmaf(e, tv, wa[p]);                          // sum e*beta'*d
            }
        }
    }

    float4 o4;
    float o[4];
    #pragma unroll
    for (int p = 0; p < 4; ++p) {
        const float mean = S[p] * 0.04f;
        const float med  = fmaf(wa[p] * __builtin_amdgcn_rcpf(ws[p]), inv_bp, mean);
        o[p] = fmaf(lam, med - m[p], m[p]);
    }
    o4.x = o[0]; o4.y = o[1]; o4.z = o[2]; o4.w = o[3];
    *(float4*)orow = o4;
}

__global__ __launch_bounds__(256, 4)
void maxmedian_kernel(const float* __restrict__ x,
                      const float* __restrict__ mix,
                      const float* __restrict__ beta_raw,
                      float* __restrict__ out,
                      int C) {
    __shared__ __align__(16) float tile[LH * LW];

    const int tiles_x = HW / TW;                       // 4
    const int tiles_per_plane = tiles_x * (HW / TH);   // 32
    const int plane = blockIdx.x / tiles_per_plane;
    const int t     = blockIdx.x % tiles_per_plane;
    const int ty0 = (t / tiles_x) * TH;
    const int tx0 = (t % tiles_x) * TW;

    const float* __restrict__ xp = x + (size_t)plane * (HW * HW);
    const int tid = threadIdx.x;

    // ---- Stage (TH+4) x (TW+4) with reflect padding ----
    {
        const int c   = tid & 63;
        const int r0s = tid >> 6;             // 0..3
        const int gx  = tx0 + c;
        #pragma unroll
        for (int k = 0; k < 9; ++k) {
            const int r  = r0s + 4 * k;       // 0..35
            const int gy = reflect_idx(ty0 + r - 2);
            tile[r * LW + c + 2] = xp[gy * HW + gx];
        }
        if (tid < 144) {                      // cols {0,1,66,67} x 36 rows
            const int jj = tid & 3;
            const int j  = (jj < 2) ? jj : (64 + jj);
            const int r  = tid >> 2;
            const int gx2 = reflect_idx(tx0 + j - 2);
            const int gy2 = reflect_idx(ty0 + r - 2);
            tile[r * LW + j] = xp[gy2 * HW + gx2];
        }
    }
    __syncthreads();

    // ---- Parameters ----
    const int ch = plane % C;
    const float lam  = 1.0f / (1.0f + __expf(-mix[ch]));
    const float beta = 5.0f + 45.0f / (1.0f + __expf(-beta_raw[0]));
    const float bp     = beta * 1.44269504088896f;   // beta * log2(e) > 0
    const float inv_bp = 1.0f / bp;
    const float c04b   = 0.04f * bp;

    // ---- Each thread: 4-wide x 2-tall ----
    const int tx  = tid & 15;
    const int ryq = tid >> 4;        // 0..15
    const int r0  = ryq * 2;
    const float* lbase = &tile[r0 * LW + 4 * tx];

    float4 w0a = *(const float4*)(lbase + 0 * LW);
    float4 w0b = *(const float4*)(lbase + 0 * LW + 4);
    float4 w1a = *(const float4*)(lbase + 1 * LW);
    float4 w1b = *(const float4*)(lbase + 1 * LW + 4);
    float4 w2a = *(const float4*)(lbase + 2 * LW);
    float4 w2b = *(const float4*)(lbase + 2 * LW + 4);
    float4 w3a = *(const float4*)(lbase + 3 * LW);
    float4 w3b = *(const float4*)(lbase + 3 * LW + 4);
    float4 w4a = *(const float4*)(lbase + 4 * LW);
    float4 w4b = *(const float4*)(lbase + 4 * LW + 4);
    float4 w5a = *(const float4*)(lbase + 5 * LW);   // prefetch row 5 early
    float4 w5b = *(const float4*)(lbase + 5 * LW + 4);

    float4 csA = add4(add4(add4(w0a, w1a), add4(w2a, w3a)), w4a);
    float4 csB = add4(add4(add4(w0b, w1b), add4(w2b, w3b)), w4b);

    // Shared vertical pair-maxes for the two output rows
    const float4 p12a = max4(w1a, w2a), p12b = max4(w1b, w2b);
    const float4 p34a = max4(w3a, w4a), p34b = max4(w3b, w4b);
    const float4 cm0a = max34(w0a, p12a, p34a);
    const float4 cm0b = max34(w0b, p12b, p34b);

    float* __restrict__ orow =
        out + (size_t)plane * (HW * HW) + (size_t)(ty0 + r0) * HW + (tx0 + 4 * tx);

    proc_row(w0a,w0b, w1a,w1b, w2a,w2b, w3a,w3b, w4a,w4b,
             cm0a, cm0b, csA, csB, bp, c04b, inv_bp, lam, orow);

    csA = add4(csA, sub4(w5a, w0a));
    csB = add4(csB, sub4(w5b, w0b));
    const float4 cm1a = max34(p12a, p34a, w5a);
    const float4 cm1b = max34(p12b, p34b, w5b);

    proc_row(w1a,w1b, w2a,w2b, w3a,w3b, w4a,w4b, w5a,w5b,
             cm1a, cm1b, csA, csB, bp, c04b, inv_bp, lam, orow + HW);
}

extern "C" void kernel_launch(void* const* d_in, const int* in_sizes, int n_in,
                              void* d_out, int out_size, void* d_ws, size_t ws_size,
                              hipStream_t stream) {
    const float* x        = (const float*)d_in[0];
    const float* mix      = (const float*)d_in[1];
    const float* beta_raw = (const float*)d_in[2];
    float* out            = (float*)d_out;

    const int planes = in_sizes[0] / (HW * HW);                 // 128
    const int C      = in_sizes[1];                             // 32
    const int tiles_per_plane = (HW / TW) * (HW / TH);          // 32
    const int grid = planes * tiles_per_plane;                  // 4096

    maxmedian_kernel<<<grid, 256, 0, stream>>>(x, mix, beta_raw, out, C);
}